// Round 3
// baseline (42.207 us; speedup 1.0000x reference)
//
#include <hip/hip_runtime.h>
#include <hip/hip_bf16.h>

// BERT_CRF, oct-partitioned fusion with async global_load_lds A-staging.
// B=64, T=512, H=768, L=9.
//
// K1 emis_o_kernel: grid 512 = (b, oct o), 256 threads (4 waves).
//   - W staged once as bf16 MFMA B-fragments in LDS (proven pattern).
//   - A (wv rows) staged per K-step via __builtin_amdgcn_global_load_lds
//     (16B/lane DMA) into a PER-WAVE private triple-buffered LDS tile,
//     prefetch distance 2, ordered by s_waitcnt vmcnt(N) only -- no
//     barriers in the K-loop. Source addresses pre-swizzled (XOR
//     (row&7)<<4) so the linear DMA lands swizzled and the fragment
//     ds_read_b128s are bank-conflict-free.
//   - 64 emission rows -> exp() -> LDS only (no global roundtrip).
//   - wave0 tail: numerator partials, 4 chunk products (CS=16, proven
//     code), balanced 4->2->1 combine -> one 9x9 oct matrix (~100 floats
//     to global). Combine tree chosen so K2 reproduces round-2's exact
//     arithmetic association.
// K2 comb_kernel: 64 blocks x 64 threads. Pair-combine octs->quarters
//   (same formula), then the proven serial fold of 4 + numerator +
//   election reduce -> out. cnt zeroed by K1 block 0.

#define Bn 64
#define Tn 512
#define Hn 768
#define Ln 9
#define EMS 12     // padded LDS emission row stride (floats)
#define CS 16      // time steps per chunk
#define NCHO 4     // chunks per oct
#define OT 64      // timesteps per block
#define KSTEPS 24  // 768 / 32

typedef short bf16x8 __attribute__((ext_vector_type(8)));   // 8 bf16 (4 VGPRs)
typedef float f32x4  __attribute__((ext_vector_type(4)));   // 4 fp32 acc

__device__ __forceinline__ short f2bf(float f) {
    return (short)__builtin_bit_cast(unsigned short, __float2bfloat16(f));
}

// async 16B/lane global->LDS DMA: lds dest = lp + lane*16 (wave-uniform lp)
#define GLOAD16(gp, lp)                                                        \
    __builtin_amdgcn_global_load_lds(                                          \
        (const __attribute__((address_space(1))) void*)(gp),                   \
        (__attribute__((address_space(3))) void*)(lp), 16, 0, 0)

// Proven pair-combine: (A,lgA) then (B,lgB) -> out (row-scaled) + outLg.
// Bit-identical op order to the round-2 in-block stage.
__device__ __forceinline__ void pair_combine(
    const float (*MA)[Ln], const float* lgA,
    const float (*MB)[Ln], const float* lgB,
    int r, float* outM, float* outLg)
{
    float mB = lgB[0];
#pragma unroll
    for (int k = 1; k < 9; ++k) mB = fmaxf(mB, lgB[k]);
    float tA[9];
#pragma unroll
    for (int k = 0; k < 9; ++k) tA[k] = MA[r][k] * __expf(lgB[k] - mB);
    float v[9];
#pragma unroll
    for (int jj = 0; jj < 9; ++jj) {
        float acc = tA[0] * MB[0][jj];
#pragma unroll
        for (int k = 1; k < 9; ++k) acc += tA[k] * MB[k][jj];
        v[jj] = acc;
    }
    float mx = v[0];
#pragma unroll
    for (int jj = 1; jj < 9; ++jj) mx = fmaxf(mx, v[jj]);
    float inv = 1.f / mx;
#pragma unroll
    for (int jj = 0; jj < 9; ++jj) outM[jj] = v[jj] * inv;
    *outLg = lgA[r] + mB + __logf(mx);
}

// ---------------- K1: per-(batch,oct) emissions + chunk products ----------------
__global__ __launch_bounds__(256) void emis_o_kernel(
    const float* __restrict__ wv, const float* __restrict__ Wm,
    const float* __restrict__ bias, const int* __restrict__ mask,
    const int* __restrict__ label, const float* __restrict__ trans,
    const float* __restrict__ startT,
    float* __restrict__ Mq, float* __restrict__ lgq,
    float* __restrict__ numq, int* __restrict__ msq,
    float* __restrict__ em0, int* __restrict__ cnt)
{
    __shared__ bf16x8 wlds[KSTEPS * 64];                 // 24576 B, W B-frags
    __shared__ __align__(16) float bufA[4][3][512];      // wave x slot x 2KB
    __shared__ float ldsE[OT][EMS];                      // exp(emissions)
    __shared__ int   ldsM[OT];
    __shared__ float eTs[81];
    __shared__ float sM[NCHO][Ln][Ln];
    __shared__ float sLg[NCHO][Ln];
    __shared__ float s2M[2][Ln][Ln];
    __shared__ float s2Lg[2][Ln];

    const int tid   = threadIdx.x;
    const int lane  = tid & 63;
    const int wid   = tid >> 6;
    const int bid   = blockIdx.x;
    const int b     = bid >> 3;
    const int o     = bid & 7;
    const int tbase = o * OT;

    if (bid == 0 && tid == 0) cnt[0] = 0;    // K2 runs strictly after K1
    if (tid < 81) eTs[tid] = __expf(trans[tid]);

    // Stage W (L=9 x H=768 fp32) as bf16 B-fragments in MFMA lane order.
    for (int idx = tid; idx < KSTEPS * 64; idx += 256) {
        const int kk = idx >> 6, ln = idx & 63;
        const int n = ln & 15, kb2 = ln >> 4;
        bf16x8 v;
        if (n < Ln) {
            const float* src = Wm + n * Hn + kk * 32 + kb2 * 8;
#pragma unroll
            for (int j = 0; j < 8; ++j) v[j] = f2bf(src[j]);
        } else {
#pragma unroll
            for (int j = 0; j < 8; ++j) v[j] = 0;
        }
        wlds[idx] = v;
    }
    __syncthreads();

    // ---- emission: wave wid computes rows [bid*64 + wid*16, +16) ----
    {
        const int rowbase = bid * OT + wid * 16;
        // DMA source swizzle: dest byte d in wave tile -> row r=d>>7,
        // physical inner=d&127, logical inner = phys ^ ((r&7)<<4).
        const int rr   = lane >> 3;                               // 0..7
        const int colf = (((lane & 7) * 16) ^ (rr << 4)) >> 2;    // float col
        const float* g0 = wv + (size_t)(rowbase + rr) * Hn + colf;      // rows 0..7
        const float* g1 = g0 + 8 * Hn;                                   // rows 8..15
        float* lb = &bufA[wid][0][0];

        // reader fragment addresses (swizzled)
        const int m  = lane & 15;
        const int kb = lane >> 4;
        const int ph0 = m * 32 + (((kb * 32)      ^ ((m & 7) << 4)) >> 2);
        const int ph1 = m * 32 + (((kb * 32 + 16) ^ ((m & 7) << 4)) >> 2);

        f32x4 acc = {0.f, 0.f, 0.f, 0.f};

        // prologue: prefetch steps 0,1
        GLOAD16(g0,      lb);        GLOAD16(g1,      lb + 256);
        GLOAD16(g0 + 32, lb + 512);  GLOAD16(g1 + 32, lb + 768);

#define EMIS_STEP(KK, SLOT)                                                    \
        {                                                                      \
            const float* s_ = lb + (SLOT) * 512;                               \
            float4 x0 = *reinterpret_cast<const float4*>(s_ + ph0);            \
            float4 x1 = *reinterpret_cast<const float4*>(s_ + ph1);            \
            bf16x8 a;                                                          \
            a[0] = f2bf(x0.x); a[1] = f2bf(x0.y);                              \
            a[2] = f2bf(x0.z); a[3] = f2bf(x0.w);                              \
            a[4] = f2bf(x1.x); a[5] = f2bf(x1.y);                              \
            a[6] = f2bf(x1.z); a[7] = f2bf(x1.w);                              \
            bf16x8 bfr = wlds[(KK) * 64 + lane];                               \
            acc = __builtin_amdgcn_mfma_f32_16x16x32_bf16(a, bfr, acc, 0, 0, 0); \
        }

        for (int kk = 0; kk < KSTEPS - 2; ++kk) {
            const int sl2 = (kk + 2) % 3;
            GLOAD16(g0 + (kk + 2) * 32, lb + sl2 * 512);
            GLOAD16(g1 + (kk + 2) * 32, lb + sl2 * 512 + 256);
            asm volatile("s_waitcnt vmcnt(4)" ::: "memory");
            EMIS_STEP(kk, kk % 3);
        }
        asm volatile("s_waitcnt vmcnt(2)" ::: "memory");
        EMIS_STEP(KSTEPS - 2, (KSTEPS - 2) % 3);
        asm volatile("s_waitcnt vmcnt(0)" ::: "memory");
        EMIS_STEP(KSTEPS - 1, (KSTEPS - 1) % 3);
#undef EMIS_STEP

        // C/D layout: col = lane&15, row = (lane>>4)*4 + r. exp -> LDS.
        const int l = lane & 15;
        if (l < Ln) {
            const float bl = bias[l];
#pragma unroll
            for (int r = 0; r < 4; ++r) {
                const int lrow = wid * 16 + (lane >> 4) * 4 + r;
                ldsE[lrow][l] = __expf(acc[r] + bl);
            }
        }
    }
    __syncthreads();

    // ---------------- CRF tail: wave 0 only, no barriers ----------------
    if (wid == 0) {
        // ---- numerator partials + mask staging (one t per lane) ----
        const int gt  = tbase + lane;
        const int tag = label[b * Tn + gt];
        const int mk  = mask[b * Tn + gt];
        ldsM[lane] = mk;
        float part = 0.f; int ms = mk;
        if (gt == 0) {
            part = startT[tag] + __logf(ldsE[0][tag]);
        } else if (mk) {
            const int prev = label[b * Tn + gt - 1];
            part = trans[prev * Ln + tag] + __logf(ldsE[lane][tag]);
        }
#pragma unroll
        for (int off = 32; off > 0; off >>= 1) {
            part += __shfl_xor(part, off);
            ms   += __shfl_xor(ms, off);
        }
        if (lane == 0) { numq[bid] = part; msq[bid] = ms; }
        if (o == 0 && lane < Ln) em0[b * Ln + lane] = ldsE[0][lane];

        // ---- chunk products (lanes 0..35): 4 chunks x 16 steps ----
        if (tid < NCHO * Ln) {
            float Tr[81];
#pragma unroll
            for (int i = 0; i < 81; ++i) Tr[i] = eTs[i];
            const int r = tid % Ln;
            const int c = tid / Ln;

            float v[9];
#pragma unroll
            for (int k = 0; k < 9; ++k) v[k] = (k == r) ? 1.f : 0.f;
            float lg = 0.f;

            int t0 = tbase + c * CS; if (t0 == 0) t0 = 1;   // only (o==0,c==0)
            const int t1 = tbase + (c + 1) * CS;

            int lt = t0 - tbase;
            float4 e0v = *reinterpret_cast<const float4*>(&ldsE[lt][0]);
            float4 e1v = *reinterpret_cast<const float4*>(&ldsE[lt][4]);
            float  e8  = ldsE[lt][8];
            int    mk2 = ldsM[lt];

            for (int t = t0; t < t1; ++t) {
                float4 p0 = make_float4(0.f, 0.f, 0.f, 0.f), p1 = p0;
                float  p8 = 0.f; int pm = 0;
                if (t + 1 < t1) {
                    const int nlt = t + 1 - tbase;
                    p0 = *reinterpret_cast<const float4*>(&ldsE[nlt][0]);
                    p1 = *reinterpret_cast<const float4*>(&ldsE[nlt][4]);
                    p8 = ldsE[nlt][8];
                    pm = ldsM[nlt];
                }
                if (mk2) {
                    float e[9] = {e0v.x, e0v.y, e0v.z, e0v.w,
                                  e1v.x, e1v.y, e1v.z, e1v.w, e8};
                    float nv[9];
#pragma unroll
                    for (int jj = 0; jj < 9; ++jj) {
                        float acc = v[0] * Tr[jj];
#pragma unroll
                        for (int k = 1; k < 9; ++k) acc += v[k] * Tr[k * 9 + jj];
                        nv[jj] = acc * e[jj];
                    }
                    float mx = nv[0];
#pragma unroll
                    for (int jj = 1; jj < 9; ++jj) mx = fmaxf(mx, nv[jj]);
                    float inv = 1.f / mx;
#pragma unroll
                    for (int jj = 0; jj < 9; ++jj) v[jj] = nv[jj] * inv;
                    lg += __logf(mx);
                }
                e0v = p0; e1v = p1; e8 = p8; mk2 = pm;
            }
#pragma unroll
            for (int jj = 0; jj < 9; ++jj) sM[c][r][jj] = v[jj];
            sLg[c][r] = lg;
        }

        // ---- pair-combine 4 -> 2 (lanes 0..17), in-wave ordering ----
        if (tid < 2 * Ln) {
            const int p = tid / Ln, r = tid % Ln;
            float om[9], ol;
            pair_combine(sM[2 * p], sLg[2 * p], sM[2 * p + 1], sLg[2 * p + 1],
                         r, om, &ol);
#pragma unroll
            for (int jj = 0; jj < 9; ++jj) s2M[p][r][jj] = om[jj];
            s2Lg[p][r] = ol;
        }

        // ---- final 2 -> 1 -> global oct matrix (lanes 0..8) ----
        if (tid < Ln) {
            const int r = tid;
            float om[9], ol;
            pair_combine(s2M[0], s2Lg[0], s2M[1], s2Lg[1], r, om, &ol);
#pragma unroll
            for (int jj = 0; jj < 9; ++jj) Mq[bid * 81 + r * 9 + jj] = om[jj];
            lgq[bid * Ln + r] = ol;
        }
    }
}

// ---------------- K2: combine 8 oct matrices per batch ----------------
__global__ __launch_bounds__(64) void comb_kernel(
    const float* __restrict__ Mq, const float* __restrict__ lgq,
    const float* __restrict__ numq, const int* __restrict__ msq,
    const float* __restrict__ em0, const int* __restrict__ label,
    const float* __restrict__ startT, const float* __restrict__ endT,
    float* __restrict__ partial, int* __restrict__ cnt, float* __restrict__ out)
{
    __shared__ float cO[8][Ln][Ln];
    __shared__ float cOl[8][Ln];
    __shared__ float cQ[4][Ln][Ln];
    __shared__ float cQl[4][Ln];
    __shared__ float cem[Ln];
    __shared__ float cnum[8];
    __shared__ int   cms[8];

    const int b = blockIdx.x, tid = threadIdx.x;

    for (int i = tid; i < 8 * 81; i += 64) ((float*)cO)[i]  = Mq[b * 648 + i];
    for (int i = tid; i < 8 * 9;  i += 64) ((float*)cOl)[i] = lgq[b * 72 + i];
    if (tid < Ln) cem[tid] = em0[b * Ln + tid];
    if (tid < 8) { cnum[tid] = numq[b * 8 + tid]; cms[tid] = msq[b * 8 + tid]; }
    __syncthreads();

    // pair-combine octs -> quarters (reproduces round-2's final in-block stage)
    if (tid < 4 * Ln) {
        const int p = tid / Ln, r = tid % Ln;
        float om[9], ol;
        pair_combine(cO[2 * p], cOl[2 * p], cO[2 * p + 1], cOl[2 * p + 1],
                     r, om, &ol);
#pragma unroll
        for (int jj = 0; jj < 9; ++jj) cQ[p][r][jj] = om[jj];
        cQl[p][r] = ol;
    }
    __syncthreads();

    // serial fold of 4 quarters + denominator (proven round-2 K2 code)
    if (tid < 16) {
        const int lj = tid;
        const float NEG = -1e30f;
        float la = (lj < Ln) ? (startT[lj] + __logf(cem[lj])) : NEG;
        for (int c = 0; c < 4; ++c) {
            float mc[9];
#pragma unroll
            for (int rr = 0; rr < 9; ++rr) mc[rr] = (lj < Ln) ? cQ[c][rr][lj] : 0.f;
            float x = (lj < Ln) ? (la + cQl[c][lj]) : NEG;
            float mm = x;
#pragma unroll
            for (int off = 1; off < 16; off <<= 1) mm = fmaxf(mm, __shfl_xor(mm, off, 16));
            float w = __expf(x - mm);                 // lj>=9 -> 0
            float sacc = 0.f;
#pragma unroll
            for (int rr = 0; rr < 9; ++rr) sacc += __shfl(w, rr, 16) * mc[rr];
            la = (lj < Ln) ? (mm + __logf(sacc)) : NEG;
        }
        float x = (lj < Ln) ? (la + endT[lj]) : NEG;
        float mm = x;
#pragma unroll
        for (int off = 1; off < 16; off <<= 1) mm = fmaxf(mm, __shfl_xor(mm, off, 16));
        float se = __expf(x - mm);
#pragma unroll
        for (int off = 1; off < 16; off <<= 1) se += __shfl_xor(se, off, 16);
        if (lj == 0) {
            float denom = mm + __logf(se);
            float numer = cnum[0] + cnum[1] + cnum[2] + cnum[3]
                        + cnum[4] + cnum[5] + cnum[6] + cnum[7];
            int   sm    = cms[0] + cms[1] + cms[2] + cms[3]
                        + cms[4] + cms[5] + cms[6] + cms[7];
            int   last  = label[b * Tn + sm - 1];
            partial[b]  = denom - (numer + endT[last]);   // = -llh[b]
        }
    }

    // last block reduces partials -> out (proven election pattern)
    int old = 0;
    if (tid == 0) {
        __threadfence();
        old = atomicAdd(cnt, 1);
    }
    old = __shfl(old, 0);
    if (old == Bn - 1) {
        __threadfence();                 // acquire: other blocks' partial[] visible
        float pv = partial[tid];
#pragma unroll
        for (int off = 32; off > 0; off >>= 1) pv += __shfl_xor(pv, off);
        if (tid == 0) out[0] = pv * (1.0f / Bn);
    }
}

extern "C" void kernel_launch(void* const* d_in, const int* in_sizes, int n_in,
                              void* d_out, int out_size, void* d_ws, size_t ws_size,
                              hipStream_t stream)
{
    // inputs: 0=length(unused) 1=word2vec 2=mask 3=label 4=W 5=b 6=start 7=end 8=trans
    const float* wv    = (const float*)d_in[1];
    const int*   mask  = (const int*)d_in[2];
    const int*   label = (const int*)d_in[3];
    const float* Wm    = (const float*)d_in[4];
    const float* bias  = (const float*)d_in[5];
    const float* st    = (const float*)d_in[6];
    const float* en    = (const float*)d_in[7];
    const float* tr    = (const float*)d_in[8];

    float* ws      = (float*)d_ws;
    float* Mq      = ws;                    // 512*81 = 41472
    float* lgq     = ws + 41472;            // 512*9  = 4608
    float* numq    = ws + 46080;            // 512
    int*   msq     = (int*)(ws + 46592);    // 512
    float* em0     = ws + 47104;            // 64*9 = 576
    float* partial = ws + 47680;            // 64
    int*   cnt     = (int*)(ws + 47744);    // 1
    float* out     = (float*)d_out;

    hipLaunchKernelGGL(emis_o_kernel, dim3(512), dim3(256), 0, stream,
                       wv, Wm, bias, mask, label, tr, st,
                       Mq, lgq, numq, msq, em0, cnt);
    hipLaunchKernelGGL(comb_kernel, dim3(Bn), dim3(64), 0, stream,
                       Mq, lgq, numq, msq, em0, label, st, en,
                       partial, cnt, out);
}